// Round 7
// baseline (222.521 us; speedup 1.0000x reference)
//
#include <hip/hip_runtime.h>
#include <stdint.h>

#define B_ROWS 4096
#define D 256
#define NTOT (2 * B_ROWS)                    // 8192 rows
#define TEMP_INV 2.0f                        // 1/T
#define NRB 64                               // 128-row blocks
#define NBLK_TRI (NRB * (NRB + 1) / 2)       // 2080 triangular blocks

typedef __attribute__((ext_vector_type(8))) short bf16x8;
typedef __attribute__((ext_vector_type(4))) float f32x4;
typedef __attribute__((ext_vector_type(4))) unsigned short us4;

typedef const __attribute__((address_space(1))) char gch;
typedef __attribute__((address_space(3))) char lch;

static __device__ __forceinline__ unsigned short f2bf(float f) {
  union { float f; unsigned u; } v; v.f = f;
  unsigned r = v.u + 0x7FFFu + ((v.u >> 16) & 1u);   // RNE
  return (unsigned short)(r >> 16);
}

// ---- kernel 1: normalize rows -> bf16 zn, f32 pos; zero rowsum+counter ----
__global__ __launch_bounds__(256) void k_prep(const float* __restrict__ xi,
                                              const float* __restrict__ xj,
                                              unsigned short* __restrict__ zn,
                                              float* __restrict__ pos,
                                              float* __restrict__ rowsum,
                                              unsigned* __restrict__ counter) {
  if (blockIdx.x == 0 && threadIdx.x == 0) *counter = 0u;
  int p = blockIdx.x * 4 + (threadIdx.x >> 6);
  int lane = threadIdx.x & 63;
  float4 a = ((const float4*)(xi + (size_t)p * D))[lane];
  float4 b = ((const float4*)(xj + (size_t)p * D))[lane];
  float sa = a.x * a.x + a.y * a.y + a.z * a.z + a.w * a.w;
  float sb = b.x * b.x + b.y * b.y + b.z * b.z + b.w * b.w;
  float ab = a.x * b.x + a.y * b.y + a.z * b.z + a.w * b.w;
  #pragma unroll
  for (int m = 1; m < 64; m <<= 1) {
    sa += __shfl_xor(sa, m, 64);
    sb += __shfl_xor(sb, m, 64);
    ab += __shfl_xor(ab, m, 64);
  }
  float ia = 1.0f / fmaxf(sqrtf(sa), 1e-8f);
  float ib = 1.0f / fmaxf(sqrtf(sb), 1e-8f);
  us4 oa, ob;
  oa.x = f2bf(a.x * ia); oa.y = f2bf(a.y * ia);
  oa.z = f2bf(a.z * ia); oa.w = f2bf(a.w * ia);
  ob.x = f2bf(b.x * ib); ob.y = f2bf(b.y * ib);
  ob.z = f2bf(b.z * ib); ob.w = f2bf(b.w * ib);
  *(us4*)(zn + (size_t)p * D + lane * 4) = oa;
  *(us4*)(zn + (size_t)(p + B_ROWS) * D + lane * 4) = ob;
  if (lane == 0) {
    float d = ab * ia * ib;
    pos[p] = d;
    pos[p + B_ROWS] = d;
    rowsum[p] = 0.0f;
    rowsum[p + B_ROWS] = 0.0f;
  }
}

// ---- kernel 2: symmetric fused sim-GEMM + exp sums + last-block loss ----
// Triangular tiling: 2080 blocks, block (r,c) with c>=r computes the full
// 128x128 tile sim[rb..rb+128) x [cbase..cbase+128). exp values accumulate
// into row-sums (rows rb+*) and — for off-diagonal tiles — also into
// col-sums (rows cbase+*) via LDS partials, exploiting sim symmetry to
// halve MFMA+exp work. Inner loop is the r1-proven core byte-for-byte
// (single 32KB stage buffer, lockstep vmcnt(0)+barriers, XOR swizzle,
// no lambdas, no launch_bounds min-wave pin -> VGPR 112 codegen).
__global__ __launch_bounds__(256) void k_gemm(const unsigned short* __restrict__ zn,
                                              const float* __restrict__ pos,
                                              float* __restrict__ rowsum,
                                              unsigned* __restrict__ counter,
                                              float* __restrict__ out) {
  __shared__ char lds[64 * 512];            // 32 KB stage buffer
  __shared__ float colpart[4][128];         // per-wave col-sum partials

  // decode triangular block index -> (r, c), c >= r (simple integer scan,
  // once per block; <= 64 scalar iterations)
  int bid = blockIdx.x;
  int r = 0, rowstart = 0;
  while (rowstart + (NRB - r) <= bid) { rowstart += NRB - r; r++; }
  int c = r + (bid - rowstart);
  int rb = r * 128;
  int cbase = c * 128;

  int w = threadIdx.x >> 6;
  int lane = threadIdx.x & 63;
  int hi = lane >> 4, lo = lane & 15;

  ((float*)colpart)[threadIdx.x] = 0.0f;
  ((float*)colpart)[threadIdx.x + 256] = 0.0f;

  const char* znb = (const char*)zn;

  // A fragments (registers): lane -> row = lo, k = 32f + hi*8
  bf16x8 a0[8], a1[8];
  int r0 = rb + w * 32 + lo;
  #pragma unroll
  for (int f = 0; f < 8; f++) {
    a0[f] = *(const bf16x8*)(znb + (size_t)r0 * 512 + f * 64 + hi * 16);
    a1[f] = *(const bf16x8*)(znb + (size_t)(r0 + 16) * 512 + f * 64 + hi * 16);
  }

  float rs[2][4] = {{0.f, 0.f, 0.f, 0.f}, {0.f, 0.f, 0.f, 0.f}};

  for (int jt = 0; jt < 2; jt++) {
    int colbase = cbase + jt * 64;
    __syncthreads();   // all waves done reading LDS before overwrite
    #pragma unroll
    for (int it = 0; it < 8; it++) {
      int local = w * 8192 + it * 1024 + lane * 16;         // linear LDS offset
      int src = local ^ (((local >> 9) & 7) << 4);          // inverse-swizzled source
      __builtin_amdgcn_global_load_lds(
          (gch*)(znb + (size_t)colbase * 512 + src),
          (lch*)(lds + w * 8192 + it * 1024), 16, 0, 0);
    }
    asm volatile("s_waitcnt vmcnt(0)" ::: "memory");
    __syncthreads();

    #pragma unroll
    for (int nt = 0; nt < 4; nt++) {
      int ldrow = nt * 16 + lo;
      int sw = (ldrow & 7) << 4;
      bf16x8 b[8];
      #pragma unroll
      for (int f = 0; f < 8; f++) {
        int off = ldrow * 512 + f * 64 + hi * 16;
        b[f] = *(const bf16x8*)(lds + (off ^ sw));
      }
      f32x4 acc0 = {0.f, 0.f, 0.f, 0.f}, acc1 = {0.f, 0.f, 0.f, 0.f};
      #pragma unroll
      for (int f = 0; f < 8; f++) {
        acc0 = __builtin_amdgcn_mfma_f32_16x16x32_bf16(a0[f], b[f], acc0, 0, 0, 0);
        acc1 = __builtin_amdgcn_mfma_f32_16x16x32_bf16(a1[f], b[f], acc1, 0, 0, 0);
      }
      float cl = 0.0f;
      #pragma unroll
      for (int rr = 0; rr < 4; rr++) {
        float e0 = __expf(TEMP_INV * acc0[rr]);
        float e1 = __expf(TEMP_INV * acc1[rr]);
        rs[0][rr] += e0;
        rs[1][rr] += e1;
        cl += e0 + e1;
      }
      // reduce col partial over the 4 hi-groups (rows of this wave's 32)
      cl += __shfl_xor(cl, 16, 64);
      cl += __shfl_xor(cl, 32, 64);
      if (hi == 0) colpart[w][jt * 64 + nt * 16 + lo] += cl;
    }
  }

  // reduce row-sums across the 16 lanes of each row-group
  #pragma unroll
  for (int m = 1; m < 16; m <<= 1) {
    #pragma unroll
    for (int t = 0; t < 2; t++)
      #pragma unroll
      for (int rr = 0; rr < 4; rr++)
        rs[t][rr] += __shfl_xor(rs[t][rr], m, 64);
  }
  if (lo == 0) {
    #pragma unroll
    for (int t = 0; t < 2; t++)
      #pragma unroll
      for (int rr = 0; rr < 4; rr++)
        atomicAdd(&rowsum[rb + w * 32 + t * 16 + hi * 4 + rr], rs[t][rr]);
  }

  // off-diagonal: each exp also contributes to the transposed row (symmetry)
  __syncthreads();
  if (c != r && threadIdx.x < 128) {
    int t = threadIdx.x;
    float cs = colpart[0][t] + colpart[1][t] + colpart[2][t] + colpart[3][t];
    atomicAdd(&rowsum[cbase + t], cs);
  }

  // ---- last-block final reduction ----
  __threadfence();
  __shared__ unsigned s_done;
  if (threadIdx.x == 0) s_done = atomicAdd(counter, 1u);
  __syncthreads();
  if (s_done == NBLK_TRI - 1) {
    float acc = 0.f;
    for (int i = threadIdx.x; i < NTOT; i += 256) {
      float s = __hip_atomic_load(&rowsum[i], __ATOMIC_RELAXED,
                                  __HIP_MEMORY_SCOPE_AGENT);
      acc += __logf(s - 7.3890560989306495f) - TEMP_INV * pos[i];
    }
    #pragma unroll
    for (int m = 1; m < 64; m <<= 1) acc += __shfl_xor(acc, m, 64);
    __shared__ float red[4];
    if (lane == 0) red[w] = acc;
    __syncthreads();
    if (threadIdx.x == 0)
      out[0] = (red[0] + red[1] + red[2] + red[3]) * (1.0f / NTOT);
  }
}

extern "C" void kernel_launch(void* const* d_in, const int* in_sizes, int n_in,
                              void* d_out, int out_size, void* d_ws, size_t ws_size,
                              hipStream_t stream) {
  const float* xi = (const float*)d_in[0];
  const float* xj = (const float*)d_in[1];

  unsigned short* zn = (unsigned short*)d_ws;                        // 4 MB
  char* base = (char*)(zn + (size_t)NTOT * D);
  float* rowsum = (float*)base;                                      // 32 KB
  float* pos = (float*)(base + (size_t)NTOT * 4);                    // 32 KB
  unsigned* counter = (unsigned*)(base + (size_t)2 * NTOT * 4);      // 4 B

  k_prep<<<B_ROWS / 4, 256, 0, stream>>>(xi, xj, zn, pos, rowsum, counter);
  k_gemm<<<NBLK_TRI, 256, 0, stream>>>(zn, pos, rowsum, counter, (float*)d_out);
}

// Round 8
// 114.175 us; speedup vs baseline: 1.9489x; 1.9489x over previous
//
#include <hip/hip_runtime.h>
#include <stdint.h>

#define B_ROWS 4096
#define D 256
#define NTOT (2 * B_ROWS)                    // 8192 rows
#define TEMP_INV 2.0f                        // 1/T
#define NSPLIT 16
#define COLS_PER_BLOCK (NTOT / NSPLIT)       // 512
#define JT_COUNT (COLS_PER_BLOCK / 64)       // 8

typedef __attribute__((ext_vector_type(8))) short bf16x8;
typedef __attribute__((ext_vector_type(4))) float f32x4;
typedef __attribute__((ext_vector_type(4))) unsigned short us4;

typedef const __attribute__((address_space(1))) char gch;
typedef __attribute__((address_space(3))) char lch;

static __device__ __forceinline__ unsigned short f2bf(float f) {
  union { float f; unsigned u; } v; v.f = f;
  unsigned r = v.u + 0x7FFFu + ((v.u >> 16) & 1u);   // RNE
  return (unsigned short)(r >> 16);
}

// ---- kernel 1: normalize rows -> bf16 zn, f32 pos; zero rowsum + out ----
__global__ __launch_bounds__(256) void k_prep(const float* __restrict__ xi,
                                              const float* __restrict__ xj,
                                              unsigned short* __restrict__ zn,
                                              float* __restrict__ pos,
                                              float* __restrict__ rowsum,
                                              float* __restrict__ out) {
  if (blockIdx.x == 0 && threadIdx.x == 0) out[0] = 0.0f;
  int p = blockIdx.x * 4 + (threadIdx.x >> 6);
  int lane = threadIdx.x & 63;
  float4 a = ((const float4*)(xi + (size_t)p * D))[lane];
  float4 b = ((const float4*)(xj + (size_t)p * D))[lane];
  float sa = a.x * a.x + a.y * a.y + a.z * a.z + a.w * a.w;
  float sb = b.x * b.x + b.y * b.y + b.z * b.z + b.w * b.w;
  float ab = a.x * b.x + a.y * b.y + a.z * b.z + a.w * b.w;
  #pragma unroll
  for (int m = 1; m < 64; m <<= 1) {
    sa += __shfl_xor(sa, m, 64);
    sb += __shfl_xor(sb, m, 64);
    ab += __shfl_xor(ab, m, 64);
  }
  float ia = 1.0f / fmaxf(sqrtf(sa), 1e-8f);
  float ib = 1.0f / fmaxf(sqrtf(sb), 1e-8f);
  us4 oa, ob;
  oa.x = f2bf(a.x * ia); oa.y = f2bf(a.y * ia);
  oa.z = f2bf(a.z * ia); oa.w = f2bf(a.w * ia);
  ob.x = f2bf(b.x * ib); ob.y = f2bf(b.y * ib);
  ob.z = f2bf(b.z * ib); ob.w = f2bf(b.w * ib);
  *(us4*)(zn + (size_t)p * D + lane * 4) = oa;
  *(us4*)(zn + (size_t)(p + B_ROWS) * D + lane * 4) = ob;
  if (lane == 0) {
    float d = ab * ia * ib;
    pos[p] = d;
    pos[p + B_ROWS] = d;
    rowsum[p] = 0.0f;
    rowsum[p + B_ROWS] = 0.0f;
  }
}

// ---- kernel 2: symmetric fused sim-GEMM + exp sums (r1 loop shape) ----
// 2D grid (NSPLIT=16, 64): block (s, r) owns rows [128r,128r+128) x cols
// [512s, 512s+512). Wholly-lower blocks return; within a block, 64-col
// jt-tiles with colbase+64 <= rb are skipped (mirror tile covers them).
// Kept tiles: rowsum always; colsum -> rowsum[col] iff colbase >= rb+128
// (strictly upper; diagonal 128-squares are self-contained via rowsum).
// Inner loop = r1-proven core (single 32KB buffer, lockstep vmcnt(0) +
// barriers, XOR swizzle, no lambdas, no tail, no fence).
__global__ __launch_bounds__(256) void k_gemm(const unsigned short* __restrict__ zn,
                                              float* __restrict__ rowsum) {
  __shared__ char lds[64 * 512];            // 32 KB stage buffer
  __shared__ float colpart[4][COLS_PER_BLOCK];   // 8 KB per-wave col partials

  int rb = (int)blockIdx.y * 128;
  int cb = (int)blockIdx.x * COLS_PER_BLOCK;
  if (cb + COLS_PER_BLOCK <= rb) return;    // wholly below diagonal

  int w = threadIdx.x >> 6;
  int lane = threadIdx.x & 63;
  int hi = lane >> 4, lo = lane & 15;

  #pragma unroll
  for (int k = 0; k < 8; k++)
    ((float*)colpart)[threadIdx.x + 256 * k] = 0.0f;

  const char* znb = (const char*)zn;

  // A fragments (registers): lane -> row = lo, k = 32f + hi*8
  bf16x8 a0[8], a1[8];
  int r0 = rb + w * 32 + lo;
  #pragma unroll
  for (int f = 0; f < 8; f++) {
    a0[f] = *(const bf16x8*)(znb + (size_t)r0 * 512 + f * 64 + hi * 16);
    a1[f] = *(const bf16x8*)(znb + (size_t)(r0 + 16) * 512 + f * 64 + hi * 16);
  }

  float rs[2][4] = {{0.f, 0.f, 0.f, 0.f}, {0.f, 0.f, 0.f, 0.f}};

  for (int jt = 0; jt < JT_COUNT; jt++) {
    int colbase = cb + jt * 64;
    if (colbase + 64 <= rb) continue;       // below diagonal: mirror covers
    int dc = (colbase >= rb + 128);         // strictly upper: also col-sums
    __syncthreads();   // all waves done reading LDS before overwrite
    #pragma unroll
    for (int it = 0; it < 8; it++) {
      int local = w * 8192 + it * 1024 + lane * 16;         // linear LDS offset
      int src = local ^ (((local >> 9) & 7) << 4);          // inverse-swizzled source
      __builtin_amdgcn_global_load_lds(
          (gch*)(znb + (size_t)colbase * 512 + src),
          (lch*)(lds + w * 8192 + it * 1024), 16, 0, 0);
    }
    asm volatile("s_waitcnt vmcnt(0)" ::: "memory");
    __syncthreads();

    #pragma unroll
    for (int nt = 0; nt < 4; nt++) {
      int ldrow = nt * 16 + lo;
      int sw = (ldrow & 7) << 4;
      bf16x8 b[8];
      #pragma unroll
      for (int f = 0; f < 8; f++) {
        int off = ldrow * 512 + f * 64 + hi * 16;
        b[f] = *(const bf16x8*)(lds + (off ^ sw));
      }
      f32x4 acc0 = {0.f, 0.f, 0.f, 0.f}, acc1 = {0.f, 0.f, 0.f, 0.f};
      #pragma unroll
      for (int f = 0; f < 8; f++) {
        acc0 = __builtin_amdgcn_mfma_f32_16x16x32_bf16(a0[f], b[f], acc0, 0, 0, 0);
        acc1 = __builtin_amdgcn_mfma_f32_16x16x32_bf16(a1[f], b[f], acc1, 0, 0, 0);
      }
      float cl = 0.0f;
      #pragma unroll
      for (int rr = 0; rr < 4; rr++) {
        float e0 = __expf(TEMP_INV * acc0[rr]);
        float e1 = __expf(TEMP_INV * acc1[rr]);
        rs[0][rr] += e0;
        rs[1][rr] += e1;
        cl += e0 + e1;
      }
      if (dc) {
        // reduce col partial over the 4 hi-groups (this wave's 32 rows)
        cl += __shfl_xor(cl, 16, 64);
        cl += __shfl_xor(cl, 32, 64);
        if (hi == 0) colpart[w][jt * 64 + nt * 16 + lo] += cl;
      }
    }
  }

  // reduce row-sums across the 16 lanes of each row-group
  #pragma unroll
  for (int m = 1; m < 16; m <<= 1) {
    #pragma unroll
    for (int t = 0; t < 2; t++)
      #pragma unroll
      for (int rr = 0; rr < 4; rr++)
        rs[t][rr] += __shfl_xor(rs[t][rr], m, 64);
  }
  if (lo == 0) {
    #pragma unroll
    for (int t = 0; t < 2; t++)
      #pragma unroll
      for (int rr = 0; rr < 4; rr++)
        atomicAdd(&rowsum[rb + w * 32 + t * 16 + hi * 4 + rr], rs[t][rr]);
  }

  // flush col-sums (symmetry: exp(sim[i][j]) also belongs to row j's sum)
  __syncthreads();
  for (int t = threadIdx.x; t < COLS_PER_BLOCK; t += 256) {
    float cs = colpart[0][t] + colpart[1][t] + colpart[2][t] + colpart[3][t];
    if (cs != 0.0f) atomicAdd(&rowsum[cb + t], cs);   // exp>0, so 0 == never written
  }
}

// ---- kernel 3: final loss reduction ----
__global__ __launch_bounds__(256) void k_final(const float* __restrict__ rowsum,
                                               const float* __restrict__ pos,
                                               float* __restrict__ out) {
  int i = blockIdx.x * 256 + threadIdx.x;
  float denom = rowsum[i] - 7.3890560989306495f;   // subtract exp(2*sim_ii)
  float t = __logf(denom) - TEMP_INV * pos[i];
  #pragma unroll
  for (int m = 1; m < 64; m <<= 1) t += __shfl_xor(t, m, 64);
  __shared__ float wsum[4];
  int w = threadIdx.x >> 6, lane = threadIdx.x & 63;
  if (lane == 0) wsum[w] = t;
  __syncthreads();
  if (threadIdx.x == 0)
    atomicAdd(out, (wsum[0] + wsum[1] + wsum[2] + wsum[3]) * (1.0f / NTOT));
}

extern "C" void kernel_launch(void* const* d_in, const int* in_sizes, int n_in,
                              void* d_out, int out_size, void* d_ws, size_t ws_size,
                              hipStream_t stream) {
  const float* xi = (const float*)d_in[0];
  const float* xj = (const float*)d_in[1];

  unsigned short* zn = (unsigned short*)d_ws;                        // 4 MB
  char* base = (char*)(zn + (size_t)NTOT * D);
  float* rowsum = (float*)base;                                      // 32 KB
  float* pos = (float*)(base + (size_t)NTOT * 4);                    // 32 KB

  k_prep<<<B_ROWS / 4, 256, 0, stream>>>(xi, xj, zn, pos, rowsum, (float*)d_out);
  dim3 grid(NSPLIT, NTOT / 128);
  k_gemm<<<grid, 256, 0, stream>>>(zn, rowsum);
  k_final<<<NTOT / 256, 256, 0, stream>>>(rowsum, pos, (float*)d_out);
}